// Round 1
// baseline (100.856 us; speedup 1.0000x reference)
//
#include <hip/hip_runtime.h>

#define BB   4
#define FF   128
#define CC   8
#define LSEQ 196608        // 256*256*3
#define NCH  2048
#define CL   96            // LSEQ / NCH
#define TL   16            // positions per LDS tile in k_final
#define NSEG 32
#define SEGL 64            // NCH / NSEG
#define PAD  130           // LDS row pad: float2 reads -> 2-way conflicts (free)

// ---------------- K1: per-chunk feature sums ----------------
__global__ __launch_bounds__(64) void k_chunksum(
    const int* __restrict__ ex, const float* __restrict__ W_in,
    const float* __restrict__ b_in, const float* __restrict__ pos,
    float* __restrict__ csum)
{
    __shared__ float xv[BB][CL];
    const int ch = blockIdx.x;
    const int t  = threadIdx.x;
    const int l0 = ch * CL;
    #pragma unroll
    for (int b = 0; b < BB; ++b)
        for (int i = t; i < CL; i += 64)
            xv[b][i] = (float)ex[b * LSEQ + l0 + i] * 0.5f - 3.0f;
    __syncthreads();

    const float w0 = W_in[t], w1 = W_in[t + 64];
    const float bb0 = b_in[t], bb1 = b_in[t + 64];
    float s0[BB] = {0.f, 0.f, 0.f, 0.f};
    float s1[BB] = {0.f, 0.f, 0.f, 0.f};
    const float* pp = pos + (size_t)l0 * FF + t;
    #pragma unroll 4
    for (int l = 0; l < CL; ++l) {
        float p0 = pp[0]  + bb0;
        float p1 = pp[64] + bb1;
        pp += FF;
        #pragma unroll
        for (int b = 0; b < BB; ++b) {
            float x = xv[b][l];
            s0[b] += fmaxf(fmaf(x, w0, p0), 0.f);
            s1[b] += fmaxf(fmaf(x, w1, p1), 0.f);
        }
    }
    #pragma unroll
    for (int b = 0; b < BB; ++b) {
        csum[((size_t)b * NCH + ch) * FF + t]      = s0[b];
        csum[((size_t)b * NCH + ch) * FF + t + 64] = s1[b];
    }
}

// ---------------- K2a: segment totals ----------------
__global__ __launch_bounds__(128) void k_segsum(
    const float* __restrict__ csum, float* __restrict__ segT)
{
    const int seg = blockIdx.x, b = blockIdx.y, f = threadIdx.x;
    const float* p = csum + ((size_t)b * NCH + (size_t)seg * SEGL) * FF + f;
    float a = 0.f;
    #pragma unroll 8
    for (int i = 0; i < SEGL; ++i) a += p[(size_t)i * FF];
    segT[((size_t)b * NSEG + seg) * FF + f] = a;
}

// ---------------- K2b: exclusive scan of segment totals ----------------
__global__ __launch_bounds__(128) void k_segscan(float* __restrict__ segT)
{
    const int b = blockIdx.x, f = threadIdx.x;
    float acc = 0.f;
    for (int s = 0; s < NSEG; ++s) {
        size_t idx = ((size_t)b * NSEG + s) * FF + f;
        float v = segT[idx];
        segT[idx] = acc;
        acc += v;
    }
}

// ---------------- K2c: exclusive-ize chunk sums ----------------
__global__ __launch_bounds__(128) void k_chscan(
    float* __restrict__ csum, const float* __restrict__ segT)
{
    const int seg = blockIdx.x, b = blockIdx.y, f = threadIdx.x;
    float acc = segT[((size_t)b * NSEG + seg) * FF + f];
    float* p = csum + ((size_t)b * NCH + (size_t)seg * SEGL) * FF + f;
    #pragma unroll 8
    for (int i = 0; i < SEGL; ++i) {
        float v = p[(size_t)i * FF];
        p[(size_t)i * FF] = acc;
        acc += v;
    }
}

// ---------------- K3: scan + normalize + final dense ----------------
__global__ __launch_bounds__(64) void k_final(
    const int* __restrict__ ex, const float* __restrict__ W_in,
    const float* __restrict__ b_in, const float* __restrict__ pos,
    const float* __restrict__ Wf, const float* __restrict__ bfin,
    const float* __restrict__ csum, float* __restrict__ out)
{
    __shared__ __align__(16) float stile[BB * TL][PAD];
    __shared__ float xv[BB][CL];
    const int ch = blockIdx.x;
    const int t  = threadIdx.x;
    const int l0 = ch * CL;
    #pragma unroll
    for (int b = 0; b < BB; ++b)
        for (int i = t; i < CL; i += 64)
            xv[b][i] = (float)ex[b * LSEQ + l0 + i] * 0.5f - 3.0f;
    __syncthreads();

    const float w0 = W_in[t], w1 = W_in[t + 64];
    const float bb0 = b_in[t], bb1 = b_in[t + 64];
    float s0[BB], s1[BB];
    #pragma unroll
    for (int b = 0; b < BB; ++b) {
        s0[b] = csum[((size_t)b * NCH + ch) * FF + t];
        s1[b] = csum[((size_t)b * NCH + ch) * FF + t + 64];
    }
    const int jb = t >> 4;   // batch owned in phase B
    const int jl = t & 15;   // tile-local position owned in phase B

    for (int tile = 0; tile < CL / TL; ++tile) {
        // ---- phase A: sequential scan of TL positions, thread-per-feature ----
        #pragma unroll 4
        for (int l = 0; l < TL; ++l) {
            const int li = tile * TL + l;
            float p0 = pos[(size_t)(l0 + li) * FF + t]      + bb0;
            float p1 = pos[(size_t)(l0 + li) * FF + t + 64] + bb1;
            #pragma unroll
            for (int b = 0; b < BB; ++b) {
                float x = xv[b][li];
                s0[b] += fmaxf(fmaf(x, w0, p0), 0.f);
                s1[b] += fmaxf(fmaf(x, w1, p1), 0.f);
                stile[b * TL + l][t]      = s0[b];
                stile[b * TL + l][t + 64] = s1[b];
            }
        }
        __syncthreads();
        // ---- phase B: thread-per-(batch,position): norm + 128x8 matvec ----
        float acc[CC] = {0.f,0.f,0.f,0.f,0.f,0.f,0.f,0.f};
        float q = 0.f;
        const float* srow = &stile[jb * TL + jl][0];
        #pragma unroll 8
        for (int f2 = 0; f2 < FF / 2; ++f2) {
            float2 v = *(const float2*)&srow[2 * f2];
            const float* wr = Wf + (2 * f2) * CC;   // uniform -> scalar loads
            #pragma unroll
            for (int c = 0; c < CC; ++c)
                acc[c] += v.x * wr[c] + v.y * wr[CC + c];
            q += v.x * v.x + v.y * v.y;
        }
        float r = rsqrtf(fmaxf(q, 1e-12f));
        float o[CC];
        #pragma unroll
        for (int c = 0; c < CC; ++c) o[c] = fmaf(acc[c], r, bfin[c]);
        size_t ob = ((size_t)jb * LSEQ + l0 + tile * TL + jl) * CC;
        *(float4*)&out[ob]     = make_float4(o[0], o[1], o[2], o[3]);
        *(float4*)&out[ob + 4] = make_float4(o[4], o[5], o[6], o[7]);
        __syncthreads();
    }
}

extern "C" void kernel_launch(void* const* d_in, const int* in_sizes, int n_in,
                              void* d_out, int out_size, void* d_ws, size_t ws_size,
                              hipStream_t stream) {
    const int*   ex   = (const int*)d_in[0];
    const float* W_in = (const float*)d_in[1];
    const float* b_in = (const float*)d_in[2];
    const float* pos  = (const float*)d_in[3];
    const float* Wf   = (const float*)d_in[4];
    const float* bf   = (const float*)d_in[5];
    float* out  = (float*)d_out;
    float* csum = (float*)d_ws;                       // [B][NCH][F]  = 4 MB
    float* segT = csum + (size_t)BB * NCH * FF;       // [B][NSEG][F] = 64 KB

    k_chunksum<<<NCH, 64, 0, stream>>>(ex, W_in, b_in, pos, csum);
    k_segsum  <<<dim3(NSEG, BB), 128, 0, stream>>>(csum, segT);
    k_segscan <<<BB, 128, 0, stream>>>(segT);
    k_chscan  <<<dim3(NSEG, BB), 128, 0, stream>>>(csum, segT);
    k_final   <<<NCH, 64, 0, stream>>>(ex, W_in, b_in, pos, Wf, bf, csum, out);
}